// Round 3
// baseline (1017.446 us; speedup 1.0000x reference)
//
#include <hip/hip_runtime.h>
#include <cstdint>
#include <cstddef>

// dims (fixed by the problem)
// b=8, n=8192, dim=1024, d_light=512, d_heavy=4096, NUM_HEAVY=1024, k_eff=1152

#define DEV __device__ __forceinline__

typedef __bf16 bf16x8 __attribute__((ext_vector_type(8)));
typedef float floatx4 __attribute__((ext_vector_type(4)));

DEV unsigned short f2bf(float f) {  // f32 -> bf16 RNE
  unsigned int u = __float_as_uint(f);
  u += 0x7FFFu + ((u >> 16) & 1u);
  return (unsigned short)(u >> 16);
}

// ---------------- weight conversion (gamma folded into w1) ----------------
__global__ __launch_bounds__(256) void convw_gamma_kernel(
    const float* __restrict__ w, const float* __restrict__ gamma,
    unsigned short* __restrict__ wb, int n) {
  int i = blockIdx.x * 256 + threadIdx.x;
  if (i < n) wb[i] = f2bf(w[i] * gamma[i & 1023]);  // K=1024 contiguous
}
__global__ __launch_bounds__(256) void convw_kernel(
    const float* __restrict__ w, unsigned short* __restrict__ wb, int n) {
  int i = blockIdx.x * 256 + threadIdx.x;
  if (i < n) wb[i] = f2bf(w[i]);
}

// ---------------- prep: rmsnorm(x)*32 -> bf16, router score s = x.rt ----------------
__global__ __launch_bounds__(256) void prep_kernel(
    const float* __restrict__ x, const float* __restrict__ rt,
    unsigned short* __restrict__ xn, double* __restrict__ s) {
  const int token = blockIdx.x;  // 0..65535
  const int tid = threadIdx.x;
  const float4 v = ((const float4*)(x + (size_t)token * 1024))[tid];
  const float4 r = ((const float4*)rt)[tid];
  float ss = v.x * v.x + v.y * v.y + v.z * v.z + v.w * v.w;
  double dot = (double)v.x * r.x + (double)v.y * r.y + (double)v.z * r.z + (double)v.w * r.w;
  const int wave = tid >> 6, lane = tid & 63;
#pragma unroll
  for (int off = 32; off; off >>= 1) {
    ss += __shfl_down(ss, off);
    dot += __shfl_down(dot, off);
  }
  __shared__ float ssr[4];
  __shared__ double dr[4];
  __shared__ float scale_sh;
  if (lane == 0) { ssr[wave] = ss; dr[wave] = dot; }
  __syncthreads();
  if (tid == 0) {
    float tot = ssr[0] + ssr[1] + ssr[2] + ssr[3];
    scale_sh = 32.0f / fmaxf(sqrtf(tot), 1e-12f);  // sqrt(dim)/||x||
    s[token] = dr[0] + dr[1] + dr[2] + dr[3];
  }
  __syncthreads();
  const float sc = scale_sh;
  ushort4 o;
  o.x = f2bf(v.x * sc); o.y = f2bf(v.y * sc);
  o.z = f2bf(v.z * sc); o.w = f2bf(v.w * sc);
  ((ushort4*)(xn + (size_t)token * 1024))[tid] = o;
}

// ---------------- coor_descent: closed-form per-iteration sums ----------------
__global__ __launch_bounds__(1024) void coor_kernel(
    const double* __restrict__ s, double* __restrict__ a_out) {
  const int b = blockIdx.x, tid = threadIdx.x;
  const int wave = tid >> 6, lane = tid & 63;
  __shared__ double red[16];
  __shared__ double bcast;
  const double* sb = s + (size_t)b * 8192;
  double sv[8], es[8];
#pragma unroll
  for (int i = 0; i < 8; ++i) {
    sv[i] = sb[tid * 8 + i];
    es[i] = exp(sv[i]);  // s ~ [-140,140] -> e^s <= 1e61, safe in f64
  }
  const double logk = log(1152.0);  // min(1024*9/8, 8192)
  double a = logk - log(8192.0);    // iteration 1 (exact: all args are 0)
  for (int it = 0; it < 49; ++it) { // iterations 2..50
    const double th = -a;
    const double eth = exp(th);
    double sum = 0.0;
#pragma unroll
    for (int i = 0; i < 8; ++i) sum += (sv[i] < th) ? es[i] : eth;
#pragma unroll
    for (int off = 32; off; off >>= 1) sum += __shfl_down(sum, off);
    if (lane == 0) red[wave] = sum;
    __syncthreads();
    if (tid == 0) {
      double t = 0.0;
      for (int i = 0; i < 16; ++i) t += red[i];
      bcast = logk - log(t);
    }
    __syncthreads();
    a = bcast;
  }
  if (tid == 0) a_out[b] = a;
}

// ---------------- selection: top-1024 of exp(min(s+a,0)), ties -> lowest index ----------------
// also builds invsel[b*8192 + token] = slot (0..1023) or -1
__global__ __launch_bounds__(1024) void select_kernel(
    const double* __restrict__ s, const double* __restrict__ a_in,
    int* __restrict__ sel, int* __restrict__ invsel) {
  const int b = blockIdx.x, tid = threadIdx.x;
  const int wave = tid >> 6, lane = tid & 63;
  const double a = a_in[b];
  const double* sb = s + (size_t)b * 8192;
  const int base = tid * 8;
  double sv[8];
  bool ind[8];
  int cnt = 0;
#pragma unroll
  for (int i = 0; i < 8; ++i) {
    sv[i] = sb[base + i];
    ind[i] = (sv[i] + a >= 0.0);  // score == 1.0 exactly
    cnt += ind[i] ? 1 : 0;
  }
  __shared__ int sc[1024];
  sc[tid] = cnt;
  __syncthreads();
  for (int off = 1; off < 1024; off <<= 1) {
    int v = sc[tid];
    int add = (tid >= off) ? sc[tid - off] : 0;
    __syncthreads();
    sc[tid] = v + add;
    __syncthreads();
  }
  const int m = sc[1023];
  int p = sc[tid] - cnt;  // exclusive prefix (index-ordered)
#pragma unroll
  for (int i = 0; i < 8; ++i) {
    int w = -1;
    if (ind[i]) {
      if (p < 1024) { sel[b * 1024 + p] = base + i; w = p; }
      ++p;
    }
    invsel[b * 8192 + base + i] = w;
  }
  if (m >= 1024) return;  // expected path: m ~ 1100-2000

  // fallback (practically never): fill with largest below-threshold s, tie -> lowest idx
  __shared__ double rv[16];
  __shared__ int ri[16];
  __shared__ int gsel;
  bool taken[8] = {false, false, false, false, false, false, false, false};
  const int need = 1024 - m;
  for (int t = 0; t < need; ++t) {
    double bvv = -1.0e300;
    int bi = 0x7FFFFFFF;
#pragma unroll
    for (int i = 0; i < 8; ++i)
      if (!ind[i] && !taken[i] && sv[i] > bvv) { bvv = sv[i]; bi = base + i; }
#pragma unroll
    for (int off = 32; off; off >>= 1) {
      double ov = __shfl_down(bvv, off);
      int oi = __shfl_down(bi, off);
      if (ov > bvv || (ov == bvv && oi < bi)) { bvv = ov; bi = oi; }
    }
    if (lane == 0) { rv[wave] = bvv; ri[wave] = bi; }
    __syncthreads();
    if (tid == 0) {
      double mv = rv[0]; int mi = ri[0];
      for (int i = 1; i < 16; ++i)
        if (rv[i] > mv || (rv[i] == mv && ri[i] < mi)) { mv = rv[i]; mi = ri[i]; }
      gsel = mi;
      sel[b * 1024 + m + t] = mi;
      invsel[b * 8192 + mi] = m + t;
    }
    __syncthreads();
    const int g = gsel;
    if (g >= base && g < base + 8) taken[g - base] = true;
    __syncthreads();
  }
}

// =====================================================================
// 256x256-tile 8-phase bf16 GEMM, C = A @ B^T (+bias epilogue)
// 8 waves (2M x 4N), per-wave 128x64 output. BK=64 split in two 32-k-halves.
// LDS 128 KiB: A/B x {buf0,buf1} x {kh0,kh1}, each region M-folded [128][64]
// XOR-swizzled: phys_slot = logical_slot ^ (row&7) [both-sides involution].
// Schedule: 8 phases / 2 K-tiles; vmcnt(8) + barrier every even phase,
// loads never drained to 0 in steady state; last iter drains 8 -> 4 -> 0.
// MODE 0: bias + exact GELU -> bf16 outH
// MODE 1: bias -> f32 outF
// MODE 2: bias -> f32 outF, fused heavy add: slot=sel[row] (invsel);
//         if slot>=0 add hA+hB at heavy row
// MODE 3: split-K=2 (swz high half = K-offset K/2), split0 -> outF (+bias),
//         split1 -> outF2 (no bias)
// SELA:   A rows indirected through sel (gather fused into staging)
// =====================================================================

enum {
  RA00 = 0,      RA01 = 16384,  RA10 = 32768,  RA11 = 49152,
  RB00 = 65536,  RB01 = 81920,  RB10 = 98304,  RB11 = 114688
};

#define VMCNT(n) asm volatile("s_waitcnt vmcnt(" #n ")" ::: "memory")
#define BARR() __builtin_amdgcn_s_barrier()
#define SCHED0() __builtin_amdgcn_sched_barrier(0)

#define STG_A(DST, KOFF)                                                      \
  do {                                                                        \
    _Pragma("unroll") for (int r_ = 0; r_ < 2; ++r_)                          \
        __builtin_amdgcn_global_load_lds(                                     \
            (__attribute__((address_space(1))) void*)(Asrc[r_] + (KOFF)),     \
            (__attribute__((address_space(3))) void*)(sh + (DST) + r_ * 8192 +\
                                                     ldsW),                   \
            16, 0, 0);                                                        \
  } while (0)

#define STG_B(DST, KOFF)                                                      \
  do {                                                                        \
    _Pragma("unroll") for (int r_ = 0; r_ < 2; ++r_)                          \
        __builtin_amdgcn_global_load_lds(                                     \
            (__attribute__((address_space(1))) void*)(Bsrc[r_] + (KOFF)),     \
            (__attribute__((address_space(3))) void*)(sh + (DST) + r_ * 8192 +\
                                                     ldsW),                   \
            16, 0, 0);                                                        \
  } while (0)

// one phase: 4 A-frag ds_reads (+4 B-frag reads when LOADB), stage, 16 MFMA
#define PH(RAOFF, RBOFF, MH, LOADB, STG)                                      \
  do {                                                                        \
    bf16x8 a_[4];                                                             \
    _Pragma("unroll") for (int f_ = 0; f_ < 4; ++f_) a_[f_] =                 \
        *(const bf16x8*)(sh + (RAOFF) + f_ * 2048 + rbA);                     \
    if (LOADB) {                                                              \
      _Pragma("unroll") for (int n_ = 0; n_ < 4; ++n_) bq[n_] =               \
          *(const bf16x8*)(sh + (RBOFF) + n_ * 2048 + rbB);                   \
    }                                                                         \
    STG;                                                                      \
    __builtin_amdgcn_s_setprio(1);                                            \
    _Pragma("unroll") for (int f_ = 0; f_ < 4; ++f_)                          \
        _Pragma("unroll") for (int n_ = 0; n_ < 4; ++n_) acc[(MH) + f_][n_] = \
            __builtin_amdgcn_mfma_f32_16x16x32_bf16(a_[f_], bq[n_],           \
                                                    acc[(MH) + f_][n_], 0, 0, \
                                                    0);                       \
    __builtin_amdgcn_s_setprio(0);                                            \
  } while (0)

#define ITER_FULL(I)                                                          \
  do {                                                                        \
    const int ks4 = ((2 * (I) + 1) << 6) + 32;                                \
    const int ks1 = ((2 * (I) + 2) << 6);                                     \
    const int ks2 = ks1 + 32;                                                 \
    const int ks3 = ((2 * (I) + 3) << 6);                                     \
    PH(RA00, RB00, 0, 1, STG_A(RA11, ks4));                                   \
    PH(RA00 + 8192, RB00, 4, 0, STG_B(RB11, ks4));                            \
    VMCNT(8); BARR(); SCHED0();                                               \
    PH(RA01, RB01, 0, 1, STG_A(RA00, ks1));                                   \
    PH(RA01 + 8192, RB01, 4, 0, STG_B(RB00, ks1));                            \
    VMCNT(8); BARR(); SCHED0();                                               \
    PH(RA10, RB10, 0, 1, STG_A(RA01, ks2));                                   \
    PH(RA10 + 8192, RB10, 4, 0, STG_B(RB01, ks2));                            \
    VMCNT(8); BARR(); SCHED0();                                               \
    PH(RA11, RB11, 0, 1, STG_A(RA10, ks3));                                   \
    PH(RA11 + 8192, RB11, 4, 0, STG_B(RB10, ks3));                            \
    VMCNT(8); BARR(); SCHED0();                                               \
  } while (0)

#define ITER_LAST(I)                                                          \
  do {                                                                        \
    const int ks4 = ((2 * (I) + 1) << 6) + 32;                                \
    PH(RA00, RB00, 0, 1, STG_A(RA11, ks4));                                   \
    PH(RA00 + 8192, RB00, 4, 0, STG_B(RB11, ks4));                            \
    VMCNT(8); BARR(); SCHED0();                                               \
    PH(RA01, RB01, 0, 1, );                                                   \
    PH(RA01 + 8192, RB01, 4, 0, );                                            \
    VMCNT(4); BARR(); SCHED0();                                               \
    PH(RA10, RB10, 0, 1, );                                                   \
    PH(RA10 + 8192, RB10, 4, 0, );                                            \
    VMCNT(0); BARR(); SCHED0();                                               \
    PH(RA11, RB11, 0, 1, );                                                   \
    PH(RA11 + 8192, RB11, 4, 0, );                                            \
  } while (0)

template <int MODE, bool SELA>
__global__ __launch_bounds__(512, 2) void gemm8p_kernel(
    const unsigned short* __restrict__ A, const unsigned short* __restrict__ B,
    const float* __restrict__ bias, float* __restrict__ outF,
    unsigned short* __restrict__ outH, const int* __restrict__ sel,
    const float* __restrict__ hA, const float* __restrict__ hB,
    float* __restrict__ outF2, int M, int N, int K) {
  __shared__ alignas(16) char sh[131072];

  const int tiles_n = N >> 8;
  const int nwg = gridDim.x;           // always % 8 == 0 here; pow2 for MODE 3
  const int bid = blockIdx.x;
  const int cpx = nwg >> 3;
  const int swz = (bid & 7) * cpx + (bid >> 3);  // XCD-contiguous chunks

  int tile = swz, ksplit = 0;
  if (MODE == 3) { ksplit = swz >= (nwg >> 1); tile = swz & ((nwg >> 1) - 1); }
  const int Kloop = (MODE == 3) ? (K >> 1) : K;
  const int kbase = (MODE == 3) ? ksplit * (K >> 1) : 0;
  const int bm = tile / tiles_n, bn = tile - bm * tiles_n;

  const int tid = threadIdx.x;
  const int wave = tid >> 6, lane = tid & 63;
  const int l16 = lane & 15, q = lane >> 4;
  const int wm = wave >> 2, wn = wave & 3;

  // fragment-read bases (physical slot = logical ^ (row&7); row&7 == l16&7)
  const int slA = (((wm * 4 + q) ^ (l16 & 7)) << 4);
  const int slB = ((((wn >> 1) * 4 + q) ^ (l16 & 7)) << 4);
  const int rbA = l16 * 128 + slA;                     // + mh*8192 + fr*2048
  const int rbB = (wn & 1) * 8192 + l16 * 128 + slB;   // + nr*2048

  // staging source (inverse-swizzled): thread writes phys slot tid&7 of
  // region row j = r*64 + tid/8 -> fetch logical slot (tid&7)^((tid>>3)&7)
  const int ssrc = (tid & 7) ^ ((tid >> 3) & 7);
  const int hfold = ssrc >> 2, chunk = ssrc & 3;
  const unsigned short* Asrc[2];
  const unsigned short* Bsrc[2];
#pragma unroll
  for (int r = 0; r < 2; ++r) {
    const int growA = bm * 256 + r * 64 + (tid >> 3) + hfold * 128;
    const int growB = bn * 256 + r * 64 + (tid >> 3) + hfold * 128;
    if (SELA) {
      const int bb = growA >> 10;  // M=8192: row -> (b, sel row in xn)
      Asrc[r] = A + ((size_t)((bb << 13) + sel[growA])) * K + kbase + chunk * 8;
    } else {
      Asrc[r] = A + (size_t)growA * K + kbase + chunk * 8;
    }
    Bsrc[r] = B + (size_t)growB * K + kbase + chunk * 8;
  }
  const int ldsW = wave * 1024;  // wave-uniform LDS base; HW adds lane*16

  floatx4 acc[8][4];
#pragma unroll
  for (int i = 0; i < 8; ++i)
#pragma unroll
    for (int j = 0; j < 4; ++j) acc[i][j] = 0.0f;
  bf16x8 bq[4];

  // prologue: stage tile0.kh0, tile0.kh1, tile1.kh0 (order matters for vmcnt)
  STG_A(RA00, 0);  STG_B(RB00, 0);
  STG_A(RA01, 32); STG_B(RB01, 32);
  STG_A(RA10, 64); STG_B(RB10, 64);
  VMCNT(8); BARR(); SCHED0();

  const int NI = Kloop >> 7;  // 2 K-tiles (of 64) per iteration
#pragma unroll 1
  for (int i = 0; i < NI - 1; ++i) ITER_FULL(i);
  ITER_LAST(NI - 1);

  // epilogue: C/D layout col = l16, row = q*4 + reg
  const int gm0 = bm * 256 + wm * 128 + q * 4;
  const int gn0 = bn * 256 + wn * 64 + l16;
  float* const oF = (MODE == 3 && ksplit) ? outF2 : outF;
#pragma unroll
  for (int m = 0; m < 8; ++m) {
#pragma unroll
    for (int n = 0; n < 4; ++n) {
      const int col = gn0 + n * 16;
      const float bv = (MODE == 3 && ksplit) ? 0.0f : bias[col];
#pragma unroll
      for (int r = 0; r < 4; ++r) {
        const int row = gm0 + m * 16 + r;
        float v = acc[m][n][r] + bv;
        if (MODE == 0) {
          float g = 0.5f * v * (1.0f + erff(v * 0.70710678118654752f));
          outH[(size_t)row * N + col] = f2bf(g);
        } else if (MODE == 2) {
          const int slot = sel[row];  // invsel: row == b*8192 + token
          if (slot >= 0) {
            const size_t hrow = (((size_t)(row >> 13)) << 10) + slot;
            v += hA[(hrow << 10) + col] + hB[(hrow << 10) + col];
          }
          outF[(size_t)row * N + col] = v;
        } else {
          oF[(size_t)row * N + col] = v;
        }
      }
    }
  }
}

extern "C" void kernel_launch(void* const* d_in, const int* in_sizes, int n_in,
                              void* d_out, int out_size, void* d_ws, size_t ws_size,
                              hipStream_t stream) {
  const float* x    = (const float*)d_in[0];
  const float* rt   = (const float*)d_in[1];
  const float* g_l  = (const float*)d_in[2];
  const float* w1_l = (const float*)d_in[3];
  const float* b1_l = (const float*)d_in[4];
  const float* w2_l = (const float*)d_in[5];
  const float* b2_l = (const float*)d_in[6];
  const float* g_h  = (const float*)d_in[7];
  const float* w1_h = (const float*)d_in[8];
  const float* b1_h = (const float*)d_in[9];
  const float* w2_h = (const float*)d_in[10];
  const float* b2_h = (const float*)d_in[11];
  float* out = (float*)d_out;

  char* ws = (char*)d_ws;
  size_t off = 0;
  auto alloc = [&](size_t bytes) -> char* {
    char* p = ws + off;
    off += (bytes + 255) & ~(size_t)255;
    return p;
  };
  unsigned short* xn  = (unsigned short*)alloc((size_t)65536 * 1024 * 2);  // 134 MB
  double* s           = (double*)alloc((size_t)65536 * 8);                 // 512 KB
  double* a_out       = (double*)alloc(256);
  int* sel            = (int*)alloc(8192 * 4);
  int* invsel         = (int*)alloc((size_t)65536 * 4);                    // 256 KB
  unsigned short* w1l = (unsigned short*)alloc((size_t)512 * 1024 * 2);
  unsigned short* w2l = (unsigned short*)alloc((size_t)1024 * 512 * 2);
  unsigned short* w1h = (unsigned short*)alloc((size_t)4096 * 1024 * 2);
  unsigned short* w2h = (unsigned short*)alloc((size_t)1024 * 4096 * 2);
  // h1 shared: heavy1 writes [8192,4096] bf16, heavy2 consumes it, THEN
  // light1 overwrites with [65536,512] bf16 (same 67 MB; stream-ordered WAR)
  unsigned short* h1  = (unsigned short*)alloc((size_t)33554432 * 2);      // 67 MB
  float* hA           = (float*)alloc((size_t)8192 * 1024 * 4);            // 33.5 MB
  float* hB           = (float*)alloc((size_t)8192 * 1024 * 4);            // 33.5 MB
  if (off > ws_size) return;  // leaves output wrong with a clear signature

  convw_gamma_kernel<<<524288 / 256, 256, 0, stream>>>(w1_l, g_l, w1l, 524288);
  convw_kernel<<<524288 / 256, 256, 0, stream>>>(w2_l, w2l, 524288);
  convw_gamma_kernel<<<4194304 / 256, 256, 0, stream>>>(w1_h, g_h, w1h, 4194304);
  convw_kernel<<<4194304 / 256, 256, 0, stream>>>(w2_h, w2h, 4194304);

  prep_kernel<<<65536, 256, 0, stream>>>(x, rt, xn, s);
  coor_kernel<<<8, 1024, 0, stream>>>(s, a_out);
  select_kernel<<<8, 1024, 0, stream>>>(s, a_out, sel, invsel);

  // heavy1 (gather fused): h1 = gelu(xn[sel] @ w1h^T + b1h)   [8192 x 4096]
  gemm8p_kernel<0, true><<<512, 512, 0, stream>>>(
      xn, w1h, b1_h, nullptr, h1, sel, nullptr, nullptr, nullptr, 8192, 4096, 1024);
  // heavy2 (split-K=2): hA = h1 @ w2h[:, :2048]^T + b2h ; hB = h1 @ w2h[:, 2048:]^T
  gemm8p_kernel<3, false><<<256, 512, 0, stream>>>(
      h1, w2h, b2_h, hA, nullptr, nullptr, nullptr, nullptr, hB, 8192, 1024, 4096);
  // light1: h1 = gelu(xn @ w1l^T + b1l)   [65536 x 512] (reuses h1 buffer)
  gemm8p_kernel<0, false><<<512, 512, 0, stream>>>(
      xn, w1l, b1_l, nullptr, h1, nullptr, nullptr, nullptr, nullptr, 65536, 512, 1024);
  // light2 (fused heavy add): out = h1 @ w2l^T + b2l + (sel? hA+hB)
  gemm8p_kernel<2, false><<<1024, 512, 0, stream>>>(
      h1, w2l, b2_l, out, nullptr, invsel, hA, hB, nullptr, 65536, 1024, 512);
}

// Round 4
// 933.543 us; speedup vs baseline: 1.0899x; 1.0899x over previous
//
#include <hip/hip_runtime.h>
#include <cstdint>
#include <cstddef>

// dims (fixed by the problem)
// b=8, n=8192, dim=1024, d_light=512, d_heavy=4096, NUM_HEAVY=1024, k_eff=1152

#define DEV __device__ __forceinline__

typedef __bf16 bf16x8 __attribute__((ext_vector_type(8)));
typedef float floatx4 __attribute__((ext_vector_type(4)));

DEV unsigned short f2bf(float f) {  // f32 -> bf16 RNE
  unsigned int u = __float_as_uint(f);
  u += 0x7FFFu + ((u >> 16) & 1u);
  return (unsigned short)(u >> 16);
}

// ---------------- weight conversion (gamma folded into w1) ----------------
__global__ __launch_bounds__(256) void convw_gamma_kernel(
    const float* __restrict__ w, const float* __restrict__ gamma,
    unsigned short* __restrict__ wb, int n) {
  int i = blockIdx.x * 256 + threadIdx.x;
  if (i < n) wb[i] = f2bf(w[i] * gamma[i & 1023]);  // K=1024 contiguous
}
__global__ __launch_bounds__(256) void convw_kernel(
    const float* __restrict__ w, unsigned short* __restrict__ wb, int n) {
  int i = blockIdx.x * 256 + threadIdx.x;
  if (i < n) wb[i] = f2bf(w[i]);
}

// ---------------- prep: rmsnorm(x)*32 -> bf16, router score s = x.rt ----------------
__global__ __launch_bounds__(256) void prep_kernel(
    const float* __restrict__ x, const float* __restrict__ rt,
    unsigned short* __restrict__ xn, double* __restrict__ s) {
  const int token = blockIdx.x;  // 0..65535
  const int tid = threadIdx.x;
  const float4 v = ((const float4*)(x + (size_t)token * 1024))[tid];
  const float4 r = ((const float4*)rt)[tid];
  float ss = v.x * v.x + v.y * v.y + v.z * v.z + v.w * v.w;
  double dot = (double)v.x * r.x + (double)v.y * r.y + (double)v.z * r.z + (double)v.w * r.w;
  const int wave = tid >> 6, lane = tid & 63;
#pragma unroll
  for (int off = 32; off; off >>= 1) {
    ss += __shfl_down(ss, off);
    dot += __shfl_down(dot, off);
  }
  __shared__ float ssr[4];
  __shared__ double dr[4];
  __shared__ float scale_sh;
  if (lane == 0) { ssr[wave] = ss; dr[wave] = dot; }
  __syncthreads();
  if (tid == 0) {
    float tot = ssr[0] + ssr[1] + ssr[2] + ssr[3];
    scale_sh = 32.0f / fmaxf(sqrtf(tot), 1e-12f);  // sqrt(dim)/||x||
    s[token] = dr[0] + dr[1] + dr[2] + dr[3];
  }
  __syncthreads();
  const float sc = scale_sh;
  ushort4 o;
  o.x = f2bf(v.x * sc); o.y = f2bf(v.y * sc);
  o.z = f2bf(v.z * sc); o.w = f2bf(v.w * sc);
  ((ushort4*)(xn + (size_t)token * 1024))[tid] = o;
}

// ---------------- coor_descent: closed-form per-iteration sums ----------------
__global__ __launch_bounds__(1024) void coor_kernel(
    const double* __restrict__ s, double* __restrict__ a_out) {
  const int b = blockIdx.x, tid = threadIdx.x;
  const int wave = tid >> 6, lane = tid & 63;
  __shared__ double red[16];
  __shared__ double bcast;
  const double* sb = s + (size_t)b * 8192;
  double sv[8], es[8];
#pragma unroll
  for (int i = 0; i < 8; ++i) {
    sv[i] = sb[tid * 8 + i];
    es[i] = exp(sv[i]);  // s ~ [-140,140] -> e^s <= 1e61, safe in f64
  }
  const double logk = log(1152.0);  // min(1024*9/8, 8192)
  double a = logk - log(8192.0);    // iteration 1 (exact: all args are 0)
  for (int it = 0; it < 49; ++it) { // iterations 2..50
    const double th = -a;
    const double eth = exp(th);
    double sum = 0.0;
#pragma unroll
    for (int i = 0; i < 8; ++i) sum += (sv[i] < th) ? es[i] : eth;
#pragma unroll
    for (int off = 32; off; off >>= 1) sum += __shfl_down(sum, off);
    if (lane == 0) red[wave] = sum;
    __syncthreads();
    if (tid == 0) {
      double t = 0.0;
      for (int i = 0; i < 16; ++i) t += red[i];
      bcast = logk - log(t);
    }
    __syncthreads();
    a = bcast;
  }
  if (tid == 0) a_out[b] = a;
}

// ---------------- selection: top-1024 of exp(min(s+a,0)), ties -> lowest index ----------------
__global__ __launch_bounds__(1024) void select_kernel(
    const double* __restrict__ s, const double* __restrict__ a_in,
    int* __restrict__ sel) {
  const int b = blockIdx.x, tid = threadIdx.x;
  const int wave = tid >> 6, lane = tid & 63;
  const double a = a_in[b];
  const double* sb = s + (size_t)b * 8192;
  const int base = tid * 8;
  double sv[8];
  bool ind[8];
  int cnt = 0;
#pragma unroll
  for (int i = 0; i < 8; ++i) {
    sv[i] = sb[base + i];
    ind[i] = (sv[i] + a >= 0.0);  // score == 1.0 exactly
    cnt += ind[i] ? 1 : 0;
  }
  __shared__ int sc[1024];
  sc[tid] = cnt;
  __syncthreads();
  for (int off = 1; off < 1024; off <<= 1) {
    int v = sc[tid];
    int add = (tid >= off) ? sc[tid - off] : 0;
    __syncthreads();
    sc[tid] = v + add;
    __syncthreads();
  }
  const int m = sc[1023];
  int p = sc[tid] - cnt;  // exclusive prefix (index-ordered)
#pragma unroll
  for (int i = 0; i < 8; ++i) {
    if (ind[i]) {
      if (p < 1024) sel[b * 1024 + p] = base + i;
      ++p;
    }
  }
  if (m >= 1024) return;  // expected path: m ~ 1100-2000

  // fallback (practically never): fill with largest below-threshold s, tie -> lowest idx
  __shared__ double rv[16];
  __shared__ int ri[16];
  __shared__ int gsel;
  bool taken[8] = {false, false, false, false, false, false, false, false};
  const int need = 1024 - m;
  for (int t = 0; t < need; ++t) {
    double bvv = -1.0e300;
    int bi = 0x7FFFFFFF;
#pragma unroll
    for (int i = 0; i < 8; ++i)
      if (!ind[i] && !taken[i] && sv[i] > bvv) { bvv = sv[i]; bi = base + i; }
#pragma unroll
    for (int off = 32; off; off >>= 1) {
      double ov = __shfl_down(bvv, off);
      int oi = __shfl_down(bi, off);
      if (ov > bvv || (ov == bvv && oi < bi)) { bvv = ov; bi = oi; }
    }
    if (lane == 0) { rv[wave] = bvv; ri[wave] = bi; }
    __syncthreads();
    if (tid == 0) {
      double mv = rv[0]; int mi = ri[0];
      for (int i = 1; i < 16; ++i)
        if (rv[i] > mv || (rv[i] == mv && ri[i] < mi)) { mv = rv[i]; mi = ri[i]; }
      gsel = mi;
      sel[b * 1024 + m + t] = mi;
    }
    __syncthreads();
    const int g = gsel;
    if (g >= base && g < base + 8) taken[g - base] = true;
    __syncthreads();
  }
}

// ---------------- heavy merge: out[b, sel[r]] += hA[r] + hB[r] ----------------
// 8192 rows x 1024 cols, fully coalesced float4; ~134 MB traffic
__global__ __launch_bounds__(256) void heavy_add_kernel(
    const float* __restrict__ hA, const float* __restrict__ hB,
    const int* __restrict__ sel, float* __restrict__ out) {
  const int r = blockIdx.x;           // 0..8191
  const int b = r >> 10;
  const int idx = sel[r];             // token in [0, 8192)
  const size_t orow = ((size_t)(b << 13) + idx) << 10;
  const size_t hrow = (size_t)r << 10;
  float4 o = ((const float4*)(out + orow))[threadIdx.x];
  const float4 a = ((const float4*)(hA + hrow))[threadIdx.x];
  const float4 c = ((const float4*)(hB + hrow))[threadIdx.x];
  o.x += a.x + c.x; o.y += a.y + c.y; o.z += a.z + c.z; o.w += a.w + c.w;
  ((float4*)(out + orow))[threadIdx.x] = o;
}

// =====================================================================
// 256x256-tile 8-phase bf16 GEMM, C = A @ B^T (+bias epilogue)
// 8 waves (2M x 4N), per-wave 128x64 output. BK=64 split in two 32-k-halves.
// LDS 128 KiB: A/B x {buf0,buf1} x {kh0,kh1}, each region M-folded [128][64]
// XOR-swizzled: phys_slot = logical_slot ^ (row&7) [both-sides involution].
// Schedule: 8 phases / 2 K-tiles; staging issued FIRST in each phase
// (issue-early: HBM latency starts before ds_reads); vmcnt(8) + barrier
// every phase pair; loads never drained to 0 in steady state;
// last iter drains 8 -> 4 -> 0.
// MODE 0: bias + exact GELU -> bf16 outH
// MODE 1: bias -> f32 outF
// MODE 3: split-K=2 (swz high half = K-offset K/2), split0 -> outF (+bias),
//         split1 -> outF2 (no bias)
// SELA:   A rows indirected through sel (gather fused into staging)
// =====================================================================

enum {
  RA00 = 0,      RA01 = 16384,  RA10 = 32768,  RA11 = 49152,
  RB00 = 65536,  RB01 = 81920,  RB10 = 98304,  RB11 = 114688
};

#define VMCNT(n) asm volatile("s_waitcnt vmcnt(" #n ")" ::: "memory")
#define BARR() __builtin_amdgcn_s_barrier()
#define SCHED0() __builtin_amdgcn_sched_barrier(0)

#define STG_A(DST, KOFF)                                                      \
  do {                                                                        \
    _Pragma("unroll") for (int r_ = 0; r_ < 2; ++r_)                          \
        __builtin_amdgcn_global_load_lds(                                     \
            (__attribute__((address_space(1))) void*)(Asrc[r_] + (KOFF)),     \
            (__attribute__((address_space(3))) void*)(sh + (DST) + r_ * 8192 +\
                                                     ldsW),                   \
            16, 0, 0);                                                        \
  } while (0)

#define STG_B(DST, KOFF)                                                      \
  do {                                                                        \
    _Pragma("unroll") for (int r_ = 0; r_ < 2; ++r_)                          \
        __builtin_amdgcn_global_load_lds(                                     \
            (__attribute__((address_space(1))) void*)(Bsrc[r_] + (KOFF)),     \
            (__attribute__((address_space(3))) void*)(sh + (DST) + r_ * 8192 +\
                                                     ldsW),                   \
            16, 0, 0);                                                        \
  } while (0)

// one phase: stage issue FIRST, then 4 A-frag ds_reads (+4 B-frag when
// LOADB), then 16 MFMA under setprio
#define PH(RAOFF, RBOFF, MH, LOADB, STG)                                      \
  do {                                                                        \
    STG;                                                                      \
    bf16x8 a_[4];                                                             \
    _Pragma("unroll") for (int f_ = 0; f_ < 4; ++f_) a_[f_] =                 \
        *(const bf16x8*)(sh + (RAOFF) + f_ * 2048 + rbA);                     \
    if (LOADB) {                                                              \
      _Pragma("unroll") for (int n_ = 0; n_ < 4; ++n_) bq[n_] =               \
          *(const bf16x8*)(sh + (RBOFF) + n_ * 2048 + rbB);                   \
    }                                                                         \
    __builtin_amdgcn_s_setprio(1);                                            \
    _Pragma("unroll") for (int f_ = 0; f_ < 4; ++f_)                          \
        _Pragma("unroll") for (int n_ = 0; n_ < 4; ++n_) acc[(MH) + f_][n_] = \
            __builtin_amdgcn_mfma_f32_16x16x32_bf16(a_[f_], bq[n_],           \
                                                    acc[(MH) + f_][n_], 0, 0, \
                                                    0);                       \
    __builtin_amdgcn_s_setprio(0);                                            \
  } while (0)

#define ITER_FULL(I)                                                          \
  do {                                                                        \
    const int ks4 = ((2 * (I) + 1) << 6) + 32;                                \
    const int ks1 = ((2 * (I) + 2) << 6);                                     \
    const int ks2 = ks1 + 32;                                                 \
    const int ks3 = ((2 * (I) + 3) << 6);                                     \
    PH(RA00, RB00, 0, 1, STG_A(RA11, ks4));                                   \
    PH(RA00 + 8192, RB00, 4, 0, STG_B(RB11, ks4));                            \
    VMCNT(8); BARR(); SCHED0();                                               \
    PH(RA01, RB01, 0, 1, STG_A(RA00, ks1));                                   \
    PH(RA01 + 8192, RB01, 4, 0, STG_B(RB00, ks1));                            \
    VMCNT(8); BARR(); SCHED0();                                               \
    PH(RA10, RB10, 0, 1, STG_A(RA01, ks2));                                   \
    PH(RA10 + 8192, RB10, 4, 0, STG_B(RB01, ks2));                            \
    VMCNT(8); BARR(); SCHED0();                                               \
    PH(RA11, RB11, 0, 1, STG_A(RA10, ks3));                                   \
    PH(RA11 + 8192, RB11, 4, 0, STG_B(RB10, ks3));                            \
    VMCNT(8); BARR(); SCHED0();                                               \
  } while (0)

#define ITER_LAST(I)                                                          \
  do {                                                                        \
    const int ks4 = ((2 * (I) + 1) << 6) + 32;                                \
    PH(RA00, RB00, 0, 1, STG_A(RA11, ks4));                                   \
    PH(RA00 + 8192, RB00, 4, 0, STG_B(RB11, ks4));                            \
    VMCNT(8); BARR(); SCHED0();                                               \
    PH(RA01, RB01, 0, 1, );                                                   \
    PH(RA01 + 8192, RB01, 4, 0, );                                            \
    VMCNT(4); BARR(); SCHED0();                                               \
    PH(RA10, RB10, 0, 1, );                                                   \
    PH(RA10 + 8192, RB10, 4, 0, );                                            \
    VMCNT(0); BARR(); SCHED0();                                               \
    PH(RA11, RB11, 0, 1, );                                                   \
    PH(RA11 + 8192, RB11, 4, 0, );                                            \
  } while (0)

template <int MODE, bool SELA>
__global__ __launch_bounds__(512, 2) void gemm8p_kernel(
    const unsigned short* __restrict__ A, const unsigned short* __restrict__ B,
    const float* __restrict__ bias, float* __restrict__ outF,
    unsigned short* __restrict__ outH, const int* __restrict__ sel,
    float* __restrict__ outF2, int M, int N, int K) {
  __shared__ alignas(16) char sh[131072];

  const int tiles_n = N >> 8;
  const int nwg = gridDim.x;           // always % 8 == 0 here; pow2 for MODE 3
  const int bid = blockIdx.x;
  const int cpx = nwg >> 3;
  const int swz = (bid & 7) * cpx + (bid >> 3);  // XCD-contiguous chunks

  int tile = swz, ksplit = 0;
  if (MODE == 3) { ksplit = swz >= (nwg >> 1); tile = swz & ((nwg >> 1) - 1); }
  const int Kloop = (MODE == 3) ? (K >> 1) : K;
  const int kbase = (MODE == 3) ? ksplit * (K >> 1) : 0;
  const int bm = tile / tiles_n, bn = tile - bm * tiles_n;

  const int tid = threadIdx.x;
  const int wave = tid >> 6, lane = tid & 63;
  const int l16 = lane & 15, q = lane >> 4;
  const int wm = wave >> 2, wn = wave & 3;

  // fragment-read bases (physical slot = logical ^ (row&7); row&7 == l16&7)
  const int slA = (((wm * 4 + q) ^ (l16 & 7)) << 4);
  const int slB = ((((wn >> 1) * 4 + q) ^ (l16 & 7)) << 4);
  const int rbA = l16 * 128 + slA;                     // + mh*8192 + fr*2048
  const int rbB = (wn & 1) * 8192 + l16 * 128 + slB;   // + nr*2048

  // staging source (inverse-swizzled): thread writes phys slot tid&7 of
  // region row j = r*64 + tid/8 -> fetch logical slot (tid&7)^((tid>>3)&7)
  const int ssrc = (tid & 7) ^ ((tid >> 3) & 7);
  const int hfold = ssrc >> 2, chunk = ssrc & 3;
  const unsigned short* Asrc[2];
  const unsigned short* Bsrc[2];
#pragma unroll
  for (int r = 0; r < 2; ++r) {
    const int growA = bm * 256 + r * 64 + (tid >> 3) + hfold * 128;
    const int growB = bn * 256 + r * 64 + (tid >> 3) + hfold * 128;
    if (SELA) {
      const int bb = growA >> 10;  // M=8192: row -> (b, sel row in xn)
      Asrc[r] = A + ((size_t)((bb << 13) + sel[growA])) * K + kbase + chunk * 8;
    } else {
      Asrc[r] = A + (size_t)growA * K + kbase + chunk * 8;
    }
    Bsrc[r] = B + (size_t)growB * K + kbase + chunk * 8;
  }
  const int ldsW = wave * 1024;  // wave-uniform LDS base; HW adds lane*16

  floatx4 acc[8][4];
#pragma unroll
  for (int i = 0; i < 8; ++i)
#pragma unroll
    for (int j = 0; j < 4; ++j) acc[i][j] = 0.0f;
  bf16x8 bq[4];

  // prologue: stage tile0.kh0, tile0.kh1, tile1.kh0 (order matters for vmcnt)
  STG_A(RA00, 0);  STG_B(RB00, 0);
  STG_A(RA01, 32); STG_B(RB01, 32);
  STG_A(RA10, 64); STG_B(RB10, 64);
  VMCNT(8); BARR(); SCHED0();

  const int NI = Kloop >> 7;  // 2 K-tiles (of 64) per iteration
#pragma unroll 1
  for (int i = 0; i < NI - 1; ++i) ITER_FULL(i);
  ITER_LAST(NI - 1);

  // epilogue: C/D layout col = l16, row = q*4 + reg
  const int gm0 = bm * 256 + wm * 128 + q * 4;
  const int gn0 = bn * 256 + wn * 64 + l16;
  float* const oF = (MODE == 3 && ksplit) ? outF2 : outF;
#pragma unroll
  for (int m = 0; m < 8; ++m) {
#pragma unroll
    for (int n = 0; n < 4; ++n) {
      const int col = gn0 + n * 16;
      const float bv = (MODE == 3 && ksplit) ? 0.0f : bias[col];
#pragma unroll
      for (int r = 0; r < 4; ++r) {
        const int row = gm0 + m * 16 + r;
        float v = acc[m][n][r] + bv;
        if (MODE == 0) {
          float g = 0.5f * v * (1.0f + erff(v * 0.70710678118654752f));
          outH[(size_t)row * N + col] = f2bf(g);
        } else {
          oF[(size_t)row * N + col] = v;
        }
      }
    }
  }
}

extern "C" void kernel_launch(void* const* d_in, const int* in_sizes, int n_in,
                              void* d_out, int out_size, void* d_ws, size_t ws_size,
                              hipStream_t stream) {
  const float* x    = (const float*)d_in[0];
  const float* rt   = (const float*)d_in[1];
  const float* g_l  = (const float*)d_in[2];
  const float* w1_l = (const float*)d_in[3];
  const float* b1_l = (const float*)d_in[4];
  const float* w2_l = (const float*)d_in[5];
  const float* b2_l = (const float*)d_in[6];
  const float* g_h  = (const float*)d_in[7];
  const float* w1_h = (const float*)d_in[8];
  const float* b1_h = (const float*)d_in[9];
  const float* w2_h = (const float*)d_in[10];
  const float* b2_h = (const float*)d_in[11];
  float* out = (float*)d_out;

  char* ws = (char*)d_ws;
  size_t off = 0;
  auto alloc = [&](size_t bytes) -> char* {
    char* p = ws + off;
    off += (bytes + 255) & ~(size_t)255;
    return p;
  };
  unsigned short* xn  = (unsigned short*)alloc((size_t)65536 * 1024 * 2);  // 134 MB
  double* s           = (double*)alloc((size_t)65536 * 8);                 // 512 KB
  double* a_out       = (double*)alloc(256);
  int* sel            = (int*)alloc(8192 * 4);
  unsigned short* w1l = (unsigned short*)alloc((size_t)512 * 1024 * 2);
  unsigned short* w2l = (unsigned short*)alloc((size_t)1024 * 512 * 2);
  unsigned short* w1h = (unsigned short*)alloc((size_t)4096 * 1024 * 2);
  unsigned short* w2h = (unsigned short*)alloc((size_t)1024 * 4096 * 2);
  // h1 shared: heavy1 writes [8192,4096] bf16, heavy2 consumes it, THEN
  // light1 overwrites with [65536,512] bf16 (same 67 MB; stream-ordered WAR)
  unsigned short* h1  = (unsigned short*)alloc((size_t)33554432 * 2);      // 67 MB
  float* hA           = (float*)alloc((size_t)8192 * 1024 * 4);            // 33.5 MB
  float* hB           = (float*)alloc((size_t)8192 * 1024 * 4);            // 33.5 MB
  if (off > ws_size) return;  // leaves output wrong with a clear signature

  convw_gamma_kernel<<<524288 / 256, 256, 0, stream>>>(w1_l, g_l, w1l, 524288);
  convw_kernel<<<524288 / 256, 256, 0, stream>>>(w2_l, w2l, 524288);
  convw_gamma_kernel<<<4194304 / 256, 256, 0, stream>>>(w1_h, g_h, w1h, 4194304);
  convw_kernel<<<4194304 / 256, 256, 0, stream>>>(w2_h, w2h, 4194304);

  prep_kernel<<<65536, 256, 0, stream>>>(x, rt, xn, s);
  coor_kernel<<<8, 1024, 0, stream>>>(s, a_out);
  select_kernel<<<8, 1024, 0, stream>>>(s, a_out, sel);

  // heavy1 (gather fused): h1 = gelu(xn[sel] @ w1h^T + b1h)   [8192 x 4096]
  gemm8p_kernel<0, true><<<512, 512, 0, stream>>>(
      xn, w1h, b1_h, nullptr, h1, sel, nullptr, 8192, 4096, 1024);
  // heavy2 (split-K=2): hA = h1 @ w2h[:, :2048]^T + b2h ; hB = h1 @ w2h[:, 2048:]^T
  gemm8p_kernel<3, false><<<256, 512, 0, stream>>>(
      h1, w2h, b2_h, hA, nullptr, nullptr, hB, 8192, 1024, 4096);
  // light1: h1 = gelu(xn @ w1l^T + b1l)   [65536 x 512] (reuses h1 buffer)
  gemm8p_kernel<0, false><<<512, 512, 0, stream>>>(
      xn, w1l, b1_l, nullptr, h1, nullptr, nullptr, 65536, 512, 1024);
  // light2: out = h1 @ w2l^T + b2l
  gemm8p_kernel<1, false><<<1024, 512, 0, stream>>>(
      h1, w2l, b2_l, out, nullptr, nullptr, nullptr, 65536, 1024, 512);
  // merge heavy rows: out[b, sel] += hA + hB
  heavy_add_kernel<<<8192, 256, 0, stream>>>(hA, hB, sel, out);
}